// Round 5
// baseline (252.892 us; speedup 1.0000x reference)
//
#include <hip/hip_runtime.h>
#include <hip/hip_bf16.h>
#include <stdint.h>
#include <stddef.h>

// DCNv2 forward: B=4, H=W=96, C=256, F=256, K=9 (3x3, same, stride1, dil1), DG=1.
// R5/R8: fused sampling+GEMM failed (R5: N-dup FETCH-bound; R8: 1.1 blk/CU lockstep +
//   xp XCD-thrash FETCH=168MB). R7: swizzle killed bank conflicts, dur flat.
// R9: XCD swizzle on k_sample/k_omgemm (-5us). k_gemm 2-phase flat (stall-structural).
// R10: counted-vmcnt 3-deep REGRESSED (FETCH +72%, occupancy -10pt). k_gemm plateau confirmed.
// R11: fusion attempt #3 with both failure causes fixed:
//   - 64M x 256N(full F) tile: sampling once/px, cols-read once. 576 blocks = 2.25/CU.
//   - XCD-contiguous swizzle (same px partition as k_omgemm): xp slice ~2.5MB/XCD, L2-res.
//   - T14 schedule: gathers(c+1) issued before MFMA(c), packed after; A/B dbuf,
//     1 barrier/step, nothing long outstanding at the drain.

namespace {
constexpr int H  = 96, W = 96, C = 256, F = 256;
constexpr int HP = 98;            // padded spatial dim (1-px zero halo)
constexpr int NP = 4 * 96 * 96;   // 36864 output pixels
constexpr int KC = 9 * 256;       // 2304 = GEMM K

constexpr int NB_PAD  = 4 * HP * HP / 8;  // 4802 blocks, 8 px each
constexpr int NB_OMW  = 9 * 32;           // 288
constexpr int NB_WT   = (KC / 64) * (F / 64);  // 144
constexpr int NB_ZERO = NP * 32 * 4 / 4096;    // 1152 (float4 x 256 thr)
}

typedef __attribute__((ext_vector_type(8))) short bf16x8;
typedef __attribute__((ext_vector_type(4))) float floatx4;

__device__ __forceinline__ void load_lds16(const void* g, void* l) {
  __builtin_amdgcn_global_load_lds((const __attribute__((address_space(1))) void*)g,
                                   (__attribute__((address_space(3))) void*)l,
                                   16, 0, 0);
}

__device__ __forceinline__ uint32_t pk2(float lo, float hi) {   // v_cvt_pk_bf16_f32 (RNE)
  __hip_bfloat162 t = __float22bfloat162_rn(float2{lo, hi});
  return *reinterpret_cast<uint32_t*>(&t);
}

__device__ __forceinline__ void acc8(uint4 v, float w, float* a) {
  a[0] += w * __uint_as_float(v.x << 16); a[1] += w * __uint_as_float(v.x & 0xffff0000u);
  a[2] += w * __uint_as_float(v.y << 16); a[3] += w * __uint_as_float(v.y & 0xffff0000u);
  a[4] += w * __uint_as_float(v.z << 16); a[5] += w * __uint_as_float(v.z & 0xffff0000u);
  a[6] += w * __uint_as_float(v.w << 16); a[7] += w * __uint_as_float(v.w & 0xffff0000u);
}

// ---------------- k_prep: pad + omw + wt + pOm-zero in one dispatch ----------------
__global__ __launch_bounds__(256) void k_prep(const float* __restrict__ x,
                                              const float* __restrict__ omk,
                                              const float* __restrict__ kern,
                                              uint4* __restrict__ xp4,
                                              __hip_bfloat16* __restrict__ wom,
                                              __hip_bfloat16* __restrict__ wt,
                                              float4* __restrict__ pOmz) {
  __shared__ float t[64][65];
  const int bi = blockIdx.x, tid = threadIdx.x;

  if (bi < NB_PAD) {                       // ---- pad: 8 px/block, 8 ch/thread ----
    const int sub = tid >> 5, cid = tid & 31;
    const int pp  = bi * 8 + sub;
    const int b   = pp / (HP * HP);
    const int r   = pp % (HP * HP);
    const int y   = r / HP, xq = r % HP;
    uint4 o = {0u, 0u, 0u, 0u};
    if (y >= 1 && y <= H && xq >= 1 && xq <= W) {
      const float* src = x + ((size_t)((b * H + (y - 1)) * W + (xq - 1))) * C + cid * 8;
      const float4 v0 = *(const float4*)src;
      const float4 v1 = *(const float4*)(src + 4);
      o.x = pk2(v0.x, v0.y); o.y = pk2(v0.z, v0.w);
      o.z = pk2(v1.x, v1.y); o.w = pk2(v1.z, v1.w);
    }
    xp4[(size_t)pp * 32 + cid] = o;
  } else if (bi < NB_PAD + NB_OMW) {       // ---- omw: [9*256][27] -> [32][2304] ----
    const int i  = bi - NB_PAD;
    const int kk = i / 32, oc = i % 32;
    float v = (oc < 27) ? omk[(size_t)(kk * 256 + tid) * 27 + oc] : 0.f;
    wom[(size_t)oc * KC + kk * 256 + tid] = __float2bfloat16(v);
  } else if (bi < NB_PAD + NB_OMW + NB_WT) {  // ---- wt: [KC][F] -> [F][KC] bf16 ----
    const int j   = bi - NB_PAD - NB_OMW;
    const int kc0 = (j % (KC / 64)) * 64, f0 = (j / (KC / 64)) * 64;
    const int rr = tid >> 6, cc = tid & 63;
#pragma unroll
    for (int i = 0; i < 16; ++i)
      t[rr * 16 + i][cc] = kern[(size_t)(kc0 + rr * 16 + i) * F + f0 + cc];
    __syncthreads();
#pragma unroll
    for (int i = 0; i < 16; ++i) {
      const int frow = rr * 16 + i;
      wt[(size_t)(f0 + frow) * KC + kc0 + cc] = __float2bfloat16(t[cc][frow]);
    }
  } else {                                 // ---- pOm zero ----
    const int j = bi - NB_PAD - NB_OMW - NB_WT;
    pOmz[(size_t)j * 256 + tid] = (float4){0.f, 0.f, 0.f, 0.f};
  }
}

// ---------------- k_omgemm: implicit-im2col MFMA GEMM, 128(M)x32(N), split-K x6 ----------------
__global__ __launch_bounds__(256) void k_omgemm(const __hip_bfloat16* __restrict__ xp,
                                                const __hip_bfloat16* __restrict__ wom,
                                                float* __restrict__ pOm) {
  __shared__ __align__(16) char lds[20480];   // 2 x {A [128][32] 8KB, B [32][32] 2KB}
  const int tid  = threadIdx.x;
  const int xr   = blockIdx.x;
  const int xs   = (xr & 7) * 36 + (xr >> 3);     // XCD-contiguous
  const int m0   = xs * 128;
  const int s    = blockIdx.y;
  const int lane = tid & 63, wave = tid >> 6;
  const int quad = lane >> 4, l16 = lane & 15;

  const int kp = (tid & 3) ^ ((tid >> 3) & 3);
  const __hip_bfloat16* abase[2];
#pragma unroll
  for (int j = 0; j < 2; ++j) {
    const int row = (tid >> 2) + j * 64;
    const int p = m0 + row;
    const int b = p / (H * W);
    const int hw = p % (H * W);
    const int h = hw / W, w = hw % W;
    abase[j] = xp + ((size_t)(b * HP + h) * HP + w) * C + kp * 8;
  }
  const __hip_bfloat16* bbase = wom + (size_t)(tid >> 2) * KC + kp * 8;

  auto stage = [&](int buf, int k0) {
    const int kk = k0 >> 8, c0 = k0 & 255;
    const int aoff = ((kk / 3) * HP + (kk % 3)) * C + c0;
    char* base = &lds[buf * 10240];
    load_lds16(abase[0] + aoff, base + tid * 16);
    load_lds16(abase[1] + aoff, base + 4096 + tid * 16);
    if (tid < 128) load_lds16(bbase + k0, base + 8192 + tid * 16);
  };

  floatx4 acc[2][2];
#pragma unroll
  for (int i = 0; i < 2; ++i)
#pragma unroll
    for (int j = 0; j < 2; ++j) acc[i][j] = (floatx4){0.f, 0.f, 0.f, 0.f};

  const int swq = (quad ^ ((l16 >> 1) & 3)) * 16;

  const int kbeg = s * 384, kend = kbeg + 384;
  stage(0, kbeg);
  int cur = 0;
#pragma unroll 1
  for (int k0 = kbeg; k0 < kend; k0 += 32) {
    __syncthreads();                       // drains stage issued last iter (or prologue)
    if (k0 + 32 < kend) stage(cur ^ 1, k0 + 32);
    const char* base = &lds[cur * 10240];

    bf16x8 af[2], bfr[2];
#pragma unroll
    for (int mt = 0; mt < 2; ++mt)
      af[mt] = *(const bf16x8*)&base[(wave * 32 + mt * 16 + l16) * 64 + swq];
#pragma unroll
    for (int nt = 0; nt < 2; ++nt)
      bfr[nt] = *(const bf16x8*)&base[8192 + (nt * 16 + l16) * 64 + swq];
#pragma unroll
    for (int mt = 0; mt < 2; ++mt)
#pragma unroll
      for (int nt = 0; nt < 2; ++nt)
        acc[mt][nt] = __builtin_amdgcn_mfma_f32_16x16x32_bf16(af[mt], bfr[nt], acc[mt][nt], 0, 0, 0);
    cur ^= 1;
  }

#pragma unroll
  for (int mt = 0; mt < 2; ++mt)
#pragma unroll
    for (int nt = 0; nt < 2; ++nt) {
      const int gm = m0 + wave * 32 + mt * 16 + quad * 4;
      const int gn = nt * 16 + l16;
#pragma unroll
      for (int r = 0; r < 4; ++r)
        __hip_atomic_fetch_add(&pOm[(size_t)(gm + r) * 32 + gn], acc[mt][nt][r],
                               __ATOMIC_RELAXED, __HIP_MEMORY_SCOPE_AGENT);
    }
}

// ---------------- k_fused: sampling fused into A-staging, 64M x 256N(full F) ----------------
// 256 thr = 4 waves, each wave 64M x 64N. Grid 576 = 2.25 blk/CU, XCD-contiguous.
// Per K-step c (32ch of kernel-point kk): thread (px=tid>>2, chunk=tid&3) gathers 4
// corner uint4 (issued BEFORE MFMA(c-?) -- T14), weighted-sums (mask folded), packs,
// ds_writes swizzled A. B (full wt, 256x32/step) via global_load_lds. A/B double-buffered,
// one __syncthreads/step; at each drain nothing long is outstanding (stage had a full
// MFMA phase to land).
__global__ __launch_bounds__(256) void k_fused(const uint4* __restrict__ xp4,
                                               const __hip_bfloat16* __restrict__ wt,
                                               const float* __restrict__ pOm,
                                               const float* __restrict__ omb,
                                               const float* __restrict__ bias,
                                               float* __restrict__ out) {
  __shared__ __align__(16) char lds[45056];
  // A[2][64][64B] @0 (8KB); B[2][256][64B] @8192 (32KB); s_ow[2][64][4]float2 @40960 (4KB)
  float2* s_ow = (float2*)&lds[40960];

  const int tid  = threadIdx.x;
  const int xs   = (blockIdx.x & 7) * 72 + (blockIdx.x >> 3);   // XCD-contiguous
  const int m0   = xs * 64;
  const int lane = tid & 63, wn = tid >> 6;   // wave owns N-slice wn*64
  const int quad = lane >> 4, l16 = lane & 15;
  const int swq  = (quad ^ ((l16 >> 1) & 3)) * 16;

  const int spx = tid >> 2, sq = tid & 3;     // px-in-tile, 8-ch chunk / corner id
  const int p_my  = m0 + spx;
  const int b_my  = p_my / (H * W);
  const int hw_my = p_my % (H * W);
  const int h_my  = hw_my / W, w_my = hw_my % W;

  // B staging: thread covers wt rows (tid>>2)+j*64 (j=0..3), chunk-XOR'd 16B chunk
  const int bkp = (tid & 3) ^ ((tid >> 3) & 3);
  const __hip_bfloat16* bsrc = wt + (size_t)(tid >> 2) * KC + bkp * 8;

  const int aw = spx * 64 + (sq ^ ((spx >> 1) & 3)) * 16;   // my A ds_write offset

  floatx4 acc[4][4];
#pragma unroll
  for (int i = 0; i < 4; ++i)
#pragma unroll
    for (int j = 0; j < 4; ++j) acc[i][j] = (floatx4){0.f, 0.f, 0.f, 0.f};

#pragma unroll 1
  for (int kk = 0; kk < 9; ++kk) {
    {  // ---- per-k corner setup: 256 thr = 64 px x 4 corners ----
      const float dy = omb[2 * kk]     + pOm[(size_t)p_my * 32 + 2 * kk];
      const float dx = omb[2 * kk + 1] + pOm[(size_t)p_my * 32 + 2 * kk + 1];
      const float mv = omb[18 + kk]    + pOm[(size_t)p_my * 32 + 18 + kk];
      const float m  = 2.f / (1.f + __expf(-mv));
      const float sy = (float)(h_my - 1 + kk / 3) + dy;
      const float sx = (float)(w_my - 1 + kk % 3) + dx;
      const float y0f = floorf(sy), x0f = floorf(sx);
      const float fy = sy - y0f, fx = sx - x0f;
      const int y0 = (int)y0f, x0 = (int)x0f;
      const int dy2 = sq >> 1, dx2 = sq & 1;
      const int yi = y0 + dy2, xi = x0 + dx2;
      const bool valid = (yi >= 0) & (yi < H) & (xi >= 0) & (xi < W);
      const float wgt = valid ? (dy2 ? fy : 1.f - fy) * (dx2 ? fx : 1.f - fx) * m : 0.f;
      const int yc = min(max(yi + 1, 0), HP - 1);
      const int xc = min(max(xi + 1, 0), HP - 1);
      const int off = ((b_my * HP + yc) * HP + xc) * 32;   // uint4 units
      s_ow[(kk & 1) * 256 + spx * 4 + sq] = float2{__int_as_float(off), wgt};
    }
    __syncthreads();   // s_ow visible; also closes prior k's last MFMA phase

    const float4 ow01 = *(const float4*)&s_ow[(kk & 1) * 256 + spx * 4];
    const float4 ow23 = *(const float4*)&s_ow[(kk & 1) * 256 + spx * 4 + 2];
    const uint4* p0 = xp4 + __float_as_int(ow01.x) + sq;
    const uint4* p1 = xp4 + __float_as_int(ow01.z) + sq;
    const uint4* p2 = xp4 + __float_as_int(ow23.x) + sq;
    const uint4* p3 = xp4 + __float_as_int(ow23.z) + sq;
    const float w0 = ow01.y, w1 = ow01.w, w2 = ow23.y, w3 = ow23.w;

    {  // ---- prologue: produce A(0)/B(0) into parity 0 ----
      const uint4 g0 = p0[0], g1 = p1[0], g2 = p2[0], g3 = p3[0];
      const int k0 = kk * 256;
#pragma unroll
      for (int j = 0; j < 4; ++j)
        load_lds16(bsrc + (size_t)j * 64 * KC + k0, &lds[8192 + j * 4096 + tid * 16]);
      float a[8] = {0.f, 0.f, 0.f, 0.f, 0.f, 0.f, 0.f, 0.f};
      acc8(g0, w0, a); acc8(g1, w1, a); acc8(g2, w2, a); acc8(g3, w3, a);
      uint4 o;
      o.x = pk2(a[0], a[1]); o.y = pk2(a[2], a[3]);
      o.z = pk2(a[4], a[5]); o.w = pk2(a[6], a[7]);
      *(uint4*)&lds[aw] = o;
    }

#pragma unroll
    for (int c = 0; c < 8; ++c) {
      __syncthreads();   // publishes A(c)/B(c); drain is cheap (stage(c) landed during MFMA(c-1))
      uint4 h0, h1, h2, h3;
      if (c < 7) {       // issue gathers + B-stage for c+1 BEFORE MFMA(c)  (T14)
        h0 = p0[(c + 1) * 4]; h1 = p1[(c + 1) * 4];
        h2 = p2[(c + 1) * 4]; h3 = p3[(c + 1) * 4];
        const int k0 = kk * 256 + (c + 1) * 32;
        char* bb = &lds[8192 + ((c + 1) & 1) * 16384];
#pragma unroll
        for (int j = 0; j < 4; ++j)
          load_lds16(bsrc + (size_t)j * 64 * KC + k0, bb + j * 4096 + tid * 16);
      }

      const char* Ab = &lds[(c & 1) * 4096];
      const char* Bb = &lds[8192 + (c & 1) * 16384];
      bf16x8 af[4], bfr[4];
#pragma unroll
      for (int mt = 0; mt < 4; ++mt)
        af[mt] = *(const bf16x8*)&Ab[(mt * 16 + l16) * 64 + swq];
#pragma unroll
      for (int nt = 0; nt < 4; ++nt)
        bfr[nt] = *(const bf16x8*)&Bb[(wn * 64 + nt * 16 + l16) * 64 + swq];
#pragma unroll
      for (int mt = 0; mt < 4; ++mt)
#pragma unroll
        for (int nt = 0; nt < 4; ++nt)
          acc[mt][nt] = __builtin_amdgcn_mfma_f32_16x16x32_bf16(af[mt], bfr[nt], acc[mt][nt], 0, 0, 0);

      if (c < 7) {       // pack + write A(c+1) AFTER MFMA(c) (gather latency covered)
        float a[8] = {0.f, 0.f, 0.f, 0.f, 0.f, 0.f, 0.f, 0.f};
        acc8(h0, w0, a); acc8(h1, w1, a); acc8(h2, w2, a); acc8(h3, w3, a);
        uint4 o;
        o.x = pk2(a[0], a[1]); o.y = pk2(a[2], a[3]);
        o.z = pk2(a[4], a[5]); o.w = pk2(a[6], a[7]);
        *(uint4*)&lds[((c + 1) & 1) * 4096 + aw] = o;
      }
    }
  }

#pragma unroll
  for (int mt = 0; mt < 4; ++mt) {
#pragma unroll
    for (int nt = 0; nt < 4; ++nt) {
      const int gm = m0 + mt * 16 + quad * 4;
      const int gn = wn * 64 + nt * 16 + l16;
      const float bs = bias[gn];
#pragma unroll
      for (int r = 0; r < 4; ++r)
        out[(size_t)(gm + r) * F + gn] = acc[mt][nt][r] + bs;
    }
  }
}

extern "C" void kernel_launch(void* const* d_in, const int* in_sizes, int n_in,
                              void* d_out, int out_size, void* d_ws, size_t ws_size,
                              hipStream_t stream) {
  const float* x    = (const float*)d_in[0];   // [4,96,96,256]
  const float* omk  = (const float*)d_in[1];   // [3,3,256,27]
  const float* omb  = (const float*)d_in[2];   // [27]
  const float* kern = (const float*)d_in[3];   // [2304,256]
  const float* bias = (const float*)d_in[4];   // [256]
  float* out = (float*)d_out;                  // [4,96,96,256]

  char* ws = (char*)d_ws;
  size_t off = 0;
  __hip_bfloat16* wt   = (__hip_bfloat16*)(ws + off); off += (size_t)F * KC * 2;           // 1,179,648
  __hip_bfloat16* xp   = (__hip_bfloat16*)(ws + off); off += (size_t)4 * HP * HP * C * 2;  // 19,668,992
  __hip_bfloat16* wom  = (__hip_bfloat16*)(ws + off); off += (size_t)32 * KC * 2;          // 147,456
  float*          pOm  = (float*)(ws + off);          off += (size_t)NP * 32 * 4;          // 4,718,592

  k_prep  <<<dim3(NB_PAD + NB_OMW + NB_WT + NB_ZERO), 256, 0, stream>>>(
      x, omk, kern, (uint4*)xp, wom, wt, (float4*)pOm);
  k_omgemm<<<dim3(NP / 128, 6), 256, 0, stream>>>(xp, wom, pOm);
  k_fused <<<dim3(NP / 64),     256, 0, stream>>>((const uint4*)xp, wt, pOm, omb, bias, out);
}

// Round 6
// 212.973 us; speedup vs baseline: 1.1874x; 1.1874x over previous
//
#include <hip/hip_runtime.h>
#include <hip/hip_bf16.h>
#include <stdint.h>
#include <stddef.h>

// DCNv2 forward: B=4, H=W=96, C=256, F=256, K=9 (3x3, same, stride1, dil1), DG=1.
// R5/R8/R11: fusion failed 3x (FETCH-bound / occupancy-lockstep / latency-chain at
//   2.25blk/CU even with FETCH fixed to 21.8MB). Split pipeline kept for good.
// R7: chunk-XOR swizzle: bank conflicts 6.19M->0, dur flat (k_gemm stall-structural).
// R9: XCD-contiguous swizzle on k_sample/k_omgemm (-5us). R10: counted-vmcnt regressed.
// R12: the subtraction k_prep+k_omgemm = total - k_fused = 111us (R11) exposed the
//   unprofiled front half as the real cost. Suspect: 7.1M device-scope atomic fp32
//   adds in k_omgemm's split-K epilogue (G12). Fixes:
//   (a) k_omgemm: M=64 grid 576, full-K per block, NO split-K, NO atomics, plain stores.
//   (b) pOm-zero pass deleted (direct stores cover all 32 cols).
//   (c) k_prep split into k_pad/k_wprep so the front half is visible in rocprof top-5.

namespace {
constexpr int H  = 96, W = 96, C = 256, F = 256;
constexpr int HP = 98;            // padded spatial dim (1-px zero halo)
constexpr int NP = 4 * 96 * 96;   // 36864 output pixels
constexpr int KC = 9 * 256;       // 2304 = GEMM K

constexpr int NB_PAD  = 4 * HP * HP / 8;       // 4802 blocks, 8 px each
constexpr int NB_OMW  = 9 * 32;                // 288
constexpr int NB_WT   = (KC / 64) * (F / 64);  // 144
}

typedef __attribute__((ext_vector_type(8))) short bf16x8;
typedef __attribute__((ext_vector_type(4))) float floatx4;

__device__ __forceinline__ void load_lds16(const void* g, void* l) {
  __builtin_amdgcn_global_load_lds((const __attribute__((address_space(1))) void*)g,
                                   (__attribute__((address_space(3))) void*)l,
                                   16, 0, 0);
}

__device__ __forceinline__ uint32_t pk2(float lo, float hi) {   // v_cvt_pk_bf16_f32 (RNE)
  __hip_bfloat162 t = __float22bfloat162_rn(float2{lo, hi});
  return *reinterpret_cast<uint32_t*>(&t);
}

__device__ __forceinline__ void acc8(uint4 v, float w, float* a) {
  a[0] += w * __uint_as_float(v.x << 16); a[1] += w * __uint_as_float(v.x & 0xffff0000u);
  a[2] += w * __uint_as_float(v.y << 16); a[3] += w * __uint_as_float(v.y & 0xffff0000u);
  a[4] += w * __uint_as_float(v.z << 16); a[5] += w * __uint_as_float(v.z & 0xffff0000u);
  a[6] += w * __uint_as_float(v.w << 16); a[7] += w * __uint_as_float(v.w & 0xffff0000u);
}

// ---------------- k_pad: x fp32 -> xp bf16 with 1-px zero halo ----------------
__global__ __launch_bounds__(256) void k_pad(const float* __restrict__ x,
                                             uint4* __restrict__ xp4) {
  const int tid = threadIdx.x;
  const int sub = tid >> 5, cid = tid & 31;
  const int pp  = blockIdx.x * 8 + sub;
  const int b   = pp / (HP * HP);
  const int r   = pp % (HP * HP);
  const int y   = r / HP, xq = r % HP;
  uint4 o = {0u, 0u, 0u, 0u};
  if (y >= 1 && y <= H && xq >= 1 && xq <= W) {
    const float* src = x + ((size_t)((b * H + (y - 1)) * W + (xq - 1))) * C + cid * 8;
    const float4 v0 = *(const float4*)src;
    const float4 v1 = *(const float4*)(src + 4);
    o.x = pk2(v0.x, v0.y); o.y = pk2(v0.z, v0.w);
    o.z = pk2(v1.x, v1.y); o.w = pk2(v1.z, v1.w);
  }
  xp4[(size_t)pp * 32 + cid] = o;
}

// ---------------- k_wprep: omw repack + wt transpose ----------------
__global__ __launch_bounds__(256) void k_wprep(const float* __restrict__ omk,
                                               const float* __restrict__ kern,
                                               __hip_bfloat16* __restrict__ wom,
                                               __hip_bfloat16* __restrict__ wt) {
  __shared__ float t[64][65];
  const int bi = blockIdx.x, tid = threadIdx.x;

  if (bi < NB_OMW) {                       // ---- omw: [9*256][27] -> [32][2304] ----
    const int kk = bi / 32, oc = bi % 32;
    float v = (oc < 27) ? omk[(size_t)(kk * 256 + tid) * 27 + oc] : 0.f;
    wom[(size_t)oc * KC + kk * 256 + tid] = __float2bfloat16(v);
  } else {                                 // ---- wt: [KC][F] -> [F][KC] bf16 ----
    const int j   = bi - NB_OMW;
    const int kc0 = (j % (KC / 64)) * 64, f0 = (j / (KC / 64)) * 64;
    const int rr = tid >> 6, cc = tid & 63;
#pragma unroll
    for (int i = 0; i < 16; ++i)
      t[rr * 16 + i][cc] = kern[(size_t)(kc0 + rr * 16 + i) * F + f0 + cc];
    __syncthreads();
#pragma unroll
    for (int i = 0; i < 16; ++i) {
      const int frow = rr * 16 + i;
      wt[(size_t)(f0 + frow) * KC + kc0 + cc] = __float2bfloat16(t[cc][frow]);
    }
  }
}

// ---------------- k_omgemm: implicit-im2col MFMA GEMM, 64(M)x32(N), full K, no atomics ----
// Grid 576, XCD-contiguous (same px partition as k_sample). 2-phase dbuf.
// Per wave: rows wave*16..+15, acc[2] (2 MFMA/k-step). Plain fp32 stores to pOm.
__global__ __launch_bounds__(256) void k_omgemm(const __hip_bfloat16* __restrict__ xp,
                                                const __hip_bfloat16* __restrict__ wom,
                                                float* __restrict__ pOm) {
  __shared__ __align__(16) char lds[12288];   // 2 x {A [64][32] 4KB, B [32][32] 2KB}
  const int tid  = threadIdx.x;
  const int xr   = blockIdx.x;
  const int xs   = (xr & 7) * 72 + (xr >> 3);     // XCD-contiguous over 576 tiles
  const int m0   = xs * 64;
  const int lane = tid & 63, wave = tid >> 6;
  const int quad = lane >> 4, l16 = lane & 15;

  const int kp  = (tid & 3) ^ ((tid >> 3) & 3);
  const int row = tid >> 2;
  {
  }
  const int p  = m0 + row;
  const int b  = p / (H * W);
  const int hw = p % (H * W);
  const int h  = hw / W, w = hw % W;
  const __hip_bfloat16* abase = xp + ((size_t)(b * HP + h) * HP + w) * C + kp * 8;
  const __hip_bfloat16* bbase = wom + (size_t)row * KC + kp * 8;   // valid for tid<128

  auto stage = [&](int buf, int k0) {
    const int kk = k0 >> 8, c0 = k0 & 255;
    const int aoff = ((kk / 3) * HP + (kk % 3)) * C + c0;
    char* base = &lds[buf * 6144];
    load_lds16(abase + aoff, base + tid * 16);
    if (tid < 128) load_lds16(bbase + k0, base + 4096 + tid * 16);
  };

  floatx4 acc[2];
  acc[0] = (floatx4){0.f, 0.f, 0.f, 0.f};
  acc[1] = (floatx4){0.f, 0.f, 0.f, 0.f};

  const int swq = (quad ^ ((l16 >> 1) & 3)) * 16;

  stage(0, 0);
  int cur = 0;
#pragma unroll 1
  for (int k0 = 0; k0 < KC; k0 += 32) {
    __syncthreads();                       // drains stage issued last iter (or prologue)
    if (k0 + 32 < KC) stage(cur ^ 1, k0 + 32);
    const char* base = &lds[cur * 6144];

    bf16x8 af = *(const bf16x8*)&base[(wave * 16 + l16) * 64 + swq];
    bf16x8 b0 = *(const bf16x8*)&base[4096 + (l16) * 64 + swq];
    bf16x8 b1 = *(const bf16x8*)&base[4096 + (16 + l16) * 64 + swq];
    acc[0] = __builtin_amdgcn_mfma_f32_16x16x32_bf16(af, b0, acc[0], 0, 0, 0);
    acc[1] = __builtin_amdgcn_mfma_f32_16x16x32_bf16(af, b1, acc[1], 0, 0, 0);
    cur ^= 1;
  }

#pragma unroll
  for (int nt = 0; nt < 2; ++nt) {
    const int gm = m0 + wave * 16 + quad * 4;
    const int gn = nt * 16 + l16;
#pragma unroll
    for (int r = 0; r < 4; ++r)
      pOm[(size_t)(gm + r) * 32 + gn] = acc[nt][r];
  }
}

// ---------------- k_sample: 8 px/block, 8 ch/thread via uint4 full-line gathers ----------------
__global__ __launch_bounds__(256) void k_sample(const uint4* __restrict__ xp4,
                                                const float* __restrict__ pOm,
                                                const float* __restrict__ om_bias,
                                                uint4* __restrict__ cols4) {
  __shared__ float2 s_ow[8][9][4];   // per (px,k,corner): {uint4-offset, weight*mask}

  const int tid = threadIdx.x;
  const int sub = tid >> 5, cid = tid & 31;     // px-in-block, 8-ch unit
  const int bs  = (blockIdx.x & 7) * 576 + (blockIdx.x >> 3);   // XCD-contiguous

  if (tid < 72) {                               // setup: 8 px x 9 k
    const int ps = tid / 9, k = tid % 9;
    const int p  = bs * 8 + ps;
    const int b  = p / (H * W);
    const int hw = p % (H * W);
    const int h = hw / W, w = hw % W;
    const float dy = om_bias[2 * k]     + pOm[(size_t)p * 32 + 2 * k];
    const float dx = om_bias[2 * k + 1] + pOm[(size_t)p * 32 + 2 * k + 1];
    const float mv = om_bias[18 + k]    + pOm[(size_t)p * 32 + 18 + k];
    const float m  = 2.f / (1.f + __expf(-mv));
    const float sy = (float)(h - 1 + k / 3) + dy;
    const float sx = (float)(w - 1 + k % 3) + dx;
    const float y0f = floorf(sy), x0f = floorf(sx);
    const float fy = sy - y0f, fx = sx - x0f;
    const int y0 = (int)y0f, x0 = (int)x0f;
#pragma unroll
    for (int c2 = 0; c2 < 4; ++c2) {
      const int dy2 = c2 >> 1, dx2 = c2 & 1;
      const int yi = y0 + dy2, xi = x0 + dx2;
      const bool valid = (yi >= 0) & (yi < H) & (xi >= 0) & (xi < W);
      const float wgt = valid ? (dy2 ? fy : 1.f - fy) * (dx2 ? fx : 1.f - fx) * m : 0.f;
      const int yc = min(max(yi + 1, 0), HP - 1);
      const int xc = min(max(xi + 1, 0), HP - 1);
      const int off = ((b * HP + yc) * HP + xc) * 32;   // uint4 units
      s_ow[ps][k][c2] = float2{__int_as_float(off), wgt};
    }
  }
  __syncthreads();

  const int p = bs * 8 + sub;
  uint4* __restrict__ ob = cols4 + (size_t)p * 288 + cid;   // KC bf16 = 288 uint4/row

#pragma unroll 1
  for (int k = 0; k < 9; ++k) {
    const float2 ow0 = s_ow[sub][k][0], ow1 = s_ow[sub][k][1];
    const float2 ow2 = s_ow[sub][k][2], ow3 = s_ow[sub][k][3];
    float a[8] = {0.f, 0.f, 0.f, 0.f, 0.f, 0.f, 0.f, 0.f};
    acc8(xp4[(size_t)__float_as_int(ow0.x) + cid], ow0.y, a);
    acc8(xp4[(size_t)__float_as_int(ow1.x) + cid], ow1.y, a);
    acc8(xp4[(size_t)__float_as_int(ow2.x) + cid], ow2.y, a);
    acc8(xp4[(size_t)__float_as_int(ow3.x) + cid], ow3.y, a);
    uint4 o;
    o.x = pk2(a[0], a[1]); o.y = pk2(a[2], a[3]);
    o.z = pk2(a[4], a[5]); o.w = pk2(a[6], a[7]);
    ob[k * 32] = o;
  }
}

// ---------------- k_gemm: bf16 MFMA GEMM, 96(M) x 128(N), 2-phase double-buffer ----------------
__global__ __launch_bounds__(256) void k_gemm(const __hip_bfloat16* __restrict__ A,
                                              const __hip_bfloat16* __restrict__ Bt,
                                              const float* __restrict__ bias,
                                              float* __restrict__ out) {
  __shared__ __align__(16) char lds[28672];   // 2 x {A [96][32] 6KB @0, B [128][32] 8KB @6144}

  const int tid  = threadIdx.x;
  const int m0   = blockIdx.x * 96;
  const int n0   = blockIdx.y * 128;
  const int lane = tid & 63, wave = tid >> 6;
  const int wm = wave & 1, wn = wave >> 1;    // wave = 48M x 64N
  const int quad = lane >> 4, l16 = lane & 15;

  const int row = tid >> 2, kp = (tid & 3) ^ ((tid >> 3) & 3);
  const __hip_bfloat16* a0 = A  + (size_t)(m0 + row) * KC + kp * 8;
  const __hip_bfloat16* a1 = A  + (size_t)(m0 + 64 + row) * KC + kp * 8;   // tid<128
  const __hip_bfloat16* b0 = Bt + (size_t)(n0 + row) * KC + kp * 8;
  const __hip_bfloat16* b1 = Bt + (size_t)(n0 + 64 + row) * KC + kp * 8;

  auto stage = [&](int buf, int k0) {
    char* base = &lds[buf * 14336];
    load_lds16(a0 + k0, base + tid * 16);
    if (tid < 128) load_lds16(a1 + k0, base + 4096 + tid * 16);
    load_lds16(b0 + k0, base + 6144 + tid * 16);
    load_lds16(b1 + k0, base + 10240 + tid * 16);
  };

  floatx4 acc[3][4];
#pragma unroll
  for (int i = 0; i < 3; ++i)
#pragma unroll
    for (int j = 0; j < 4; ++j) acc[i][j] = (floatx4){0.f, 0.f, 0.f, 0.f};

  const int swq = (quad ^ ((l16 >> 1) & 3)) * 16;

  stage(0, 0);
  int cur = 0;
#pragma unroll 1
  for (int k0 = 0; k0 < KC; k0 += 32) {
    __syncthreads();                       // drains stage issued last iter (or prologue)
    if (k0 + 32 < KC) stage(cur ^ 1, k0 + 32);
    const char* base = &lds[cur * 14336];

    bf16x8 af[3], bfr[4];
#pragma unroll
    for (int mt = 0; mt < 3; ++mt)
      af[mt] = *(const bf16x8*)&base[(wm * 48 + mt * 16 + l16) * 64 + swq];
#pragma unroll
    for (int nt = 0; nt < 4; ++nt)
      bfr[nt] = *(const bf16x8*)&base[6144 + (wn * 64 + nt * 16 + l16) * 64 + swq];
#pragma unroll
    for (int mt = 0; mt < 3; ++mt)
#pragma unroll
      for (int nt = 0; nt < 4; ++nt)
        acc[mt][nt] = __builtin_amdgcn_mfma_f32_16x16x32_bf16(af[mt], bfr[nt], acc[mt][nt], 0, 0, 0);
    cur ^= 1;
  }

#pragma unroll
  for (int mt = 0; mt < 3; ++mt) {
#pragma unroll
    for (int nt = 0; nt < 4; ++nt) {
      const int gm = m0 + wm * 48 + mt * 16 + quad * 4;
      const int gn = n0 + wn * 64 + nt * 16 + l16;
      const float bs = bias[gn];
#pragma unroll
      for (int r = 0; r < 4; ++r)
        out[(size_t)(gm + r) * F + gn] = acc[mt][nt][r] + bs;
    }
  }
}

extern "C" void kernel_launch(void* const* d_in, const int* in_sizes, int n_in,
                              void* d_out, int out_size, void* d_ws, size_t ws_size,
                              hipStream_t stream) {
  const float* x    = (const float*)d_in[0];   // [4,96,96,256]
  const float* omk  = (const float*)d_in[1];   // [3,3,256,27]
  const float* omb  = (const float*)d_in[2];   // [27]
  const float* kern = (const float*)d_in[3];   // [2304,256]
  const float* bias = (const float*)d_in[4];   // [256]
  float* out = (float*)d_out;                  // [4,96,96,256]

  char* ws = (char*)d_ws;
  size_t off = 0;
  __hip_bfloat16* wt   = (__hip_bfloat16*)(ws + off); off += (size_t)F * KC * 2;           // 1,179,648
  __hip_bfloat16* xp   = (__hip_bfloat16*)(ws + off); off += (size_t)4 * HP * HP * C * 2;  // 19,668,992
  __hip_bfloat16* wom  = (__hip_bfloat16*)(ws + off); off += (size_t)32 * KC * 2;          // 147,456
  float*          pOm  = (float*)(ws + off);          off += (size_t)NP * 32 * 4;          // 4,718,592
  __hip_bfloat16* cols = (__hip_bfloat16*)(ws + off);                                      // 169,869,312

  k_pad   <<<dim3(NB_PAD),           256, 0, stream>>>(x, (uint4*)xp);
  k_wprep <<<dim3(NB_OMW + NB_WT),   256, 0, stream>>>(omk, kern, wom, wt);
  k_omgemm<<<dim3(576),              256, 0, stream>>>(xp, wom, pOm);
  k_sample<<<dim3(NP / 8),           256, 0, stream>>>((const uint4*)xp, pOm, omb, (uint4*)cols);
  k_gemm  <<<dim3(NP / 96, F / 128), 256, 0, stream>>>(cols, wt, bias, out);
}